// Round 3
// baseline (806.741 us; speedup 1.0000x reference)
//
#include <hip/hip_runtime.h>

#define BB 8
#define CC 192
#define C3 576
#define HH 128
#define WW 128
#define HW 16384
#define HEADS 4
#define CHD 48

// ---- K0: transpose w_qkv [576][192] -> wT [192][576]
__global__ void k0_transpose(const float* __restrict__ w, float* __restrict__ wT) {
    int idx = blockIdx.x * 256 + threadIdx.x;
    if (idx >= C3 * CC) return;
    int i = idx / C3, o = idx % C3;
    wT[idx] = w[o * CC + i];
}

// ---- GEMM: OUT[b][o][p] = sum_k WT[k][o + .] * X[b][k][p], K = 192, O-range = 192
// WT row stride = Wstride (576 for qkv sections, 192 for the M GEMM).
// grid (HW/256, 192/64, B), block 256
__global__ __launch_bounds__(256) void gemm_ko(
    const float* __restrict__ WT, long wt_bs, int Wstride,
    const float* __restrict__ X, long x_bs,
    float* __restrict__ OUT, long out_bs)
{
    __shared__ float Ws[32 * 64];
    __shared__ float Xs[32 * 256];
    const int tid = threadIdx.x;
    const int tx = tid & 31, ty = tid >> 5;
    const int pBase = blockIdx.x * 256;
    const int oBase = blockIdx.y * 64;
    const int b = blockIdx.z;
    const float* wt = WT + (size_t)b * wt_bs;
    const float* xb = X + (size_t)b * x_bs;
    float* ob = OUT + (size_t)b * out_bs;

    float4 acca[8], accb[8];
    #pragma unroll
    for (int i = 0; i < 8; i++) { acca[i] = {0,0,0,0}; accb[i] = {0,0,0,0}; }

    for (int kb = 0; kb < 192; kb += 32) {
        #pragma unroll
        for (int i = 0; i < 2; i++) {
            int f4 = i * 256 + tid;            // 0..511
            int k = f4 >> 4, of = f4 & 15;
            ((float4*)Ws)[f4] = *(const float4*)(wt + (size_t)(kb + k) * Wstride + oBase + of * 4);
        }
        #pragma unroll
        for (int i = 0; i < 8; i++) {
            int f4 = i * 256 + tid;            // 0..2047
            int k = f4 >> 6, pf = f4 & 63;
            ((float4*)Xs)[f4] = *(const float4*)(xb + (size_t)(kb + k) * HW + pBase + pf * 4);
        }
        __syncthreads();
        #pragma unroll
        for (int k = 0; k < 32; k++) {
            float4 xa  = ((float4*)Xs)[k * 64 + tx];
            float4 xbv = ((float4*)Xs)[k * 64 + 32 + tx];
            float4 w0  = ((float4*)Ws)[k * 16 + ty * 2];
            float4 w1  = ((float4*)Ws)[k * 16 + ty * 2 + 1];
            float wv[8] = {w0.x, w0.y, w0.z, w0.w, w1.x, w1.y, w1.z, w1.w};
            #pragma unroll
            for (int i = 0; i < 8; i++) {
                acca[i].x += wv[i] * xa.x;  acca[i].y += wv[i] * xa.y;
                acca[i].z += wv[i] * xa.z;  acca[i].w += wv[i] * xa.w;
                accb[i].x += wv[i] * xbv.x; accb[i].y += wv[i] * xbv.y;
                accb[i].z += wv[i] * xbv.z; accb[i].w += wv[i] * xbv.w;
            }
        }
        __syncthreads();
    }
    #pragma unroll
    for (int i = 0; i < 8; i++) {
        int o = oBase + ty * 8 + i;
        float* row = ob + (size_t)o * HW + pBase;
        ((float4*)row)[tx] = acca[i];
        ((float4*)row)[32 + tx] = accb[i];
    }
}

// ---- In-place depthwise 3x3 (SAME). One block per (b,c) plane; rolling
// 10-row LDS ring so each input row is consumed from LDS before its global
// slot is overwritten. grid (B*CC), block 256.
__global__ __launch_bounds__(256) void k_dw_ip(
    float* __restrict__ buf, const float* __restrict__ wdw, int woff)
{
    __shared__ float rows[10][WW];      // 5 KB ring
    const int plane = blockIdx.x;        // b*CC + c
    const int c = plane % CC;
    float* p = buf + (size_t)plane * HW;
    const float* wc = wdw + (size_t)(woff + c) * 9;
    float w0=wc[0],w1=wc[1],w2=wc[2],w3=wc[3],w4=wc[4],w5=wc[5],w6=wc[6],w7=wc[7],w8=wc[8];
    const int tid = threadIdx.x;
    const int lr = tid >> 5;             // 0..7  (row within chunk)
    const int lx = (tid & 31) * 4;       // 0..124

    // preload row 0 into slot 0
    if (tid < 32) ((float4*)rows[0])[tid] = ((const float4*)p)[tid];
    __syncthreads();

    for (int y0 = 0; y0 < HH; y0 += 8) {
        // load input rows y0+1 .. y0+8 into the ring
        int ry = y0 + 1 + lr;
        if (ry < HH)
            *(float4*)&rows[ry % 10][lx] = *(const float4*)(p + (size_t)ry * WW + lx);
        __syncthreads();
        // compute output rows y0 .. y0+7 from the ring
        const int oy = y0 + lr;
        float a0=0, a1=0, a2=0, a3=0;
        if (oy >= 1) {
            const float* rw = rows[(oy - 1) % 10];
            float m0=rw[lx],m1=rw[lx+1],m2=rw[lx+2],m3=rw[lx+3];
            float lf = lx ? rw[lx-1] : 0.f, rt = (lx < 124) ? rw[lx+4] : 0.f;
            a0 += w0*lf + w1*m0 + w2*m1;
            a1 += w0*m0 + w1*m1 + w2*m2;
            a2 += w0*m1 + w1*m2 + w2*m3;
            a3 += w0*m2 + w1*m3 + w2*rt;
        }
        {
            const float* rw = rows[oy % 10];
            float m0=rw[lx],m1=rw[lx+1],m2=rw[lx+2],m3=rw[lx+3];
            float lf = lx ? rw[lx-1] : 0.f, rt = (lx < 124) ? rw[lx+4] : 0.f;
            a0 += w3*lf + w4*m0 + w5*m1;
            a1 += w3*m0 + w4*m1 + w5*m2;
            a2 += w3*m1 + w4*m2 + w5*m3;
            a3 += w3*m2 + w4*m3 + w5*rt;
        }
        if (oy + 1 < HH) {
            const float* rw = rows[(oy + 1) % 10];
            float m0=rw[lx],m1=rw[lx+1],m2=rw[lx+2],m3=rw[lx+3];
            float lf = lx ? rw[lx-1] : 0.f, rt = (lx < 124) ? rw[lx+4] : 0.f;
            a0 += w6*lf + w7*m0 + w8*m1;
            a1 += w6*m0 + w7*m1 + w8*m2;
            a2 += w6*m1 + w7*m2 + w8*m3;
            a3 += w6*m2 + w7*m3 + w8*rt;
        }
        __syncthreads();   // all ring reads done before next chunk overwrites
        *(float4*)(p + (size_t)oy * WW + lx) = make_float4(a0, a1, a2, a3);
    }
}

// ---- K3: Gram (q.k^T over n) + sum q^2 + sum k^2, per (b,head)
// qdw/kdw: [B][CC][HW] each. grid (16, HEADS, B), block 256.
__global__ __launch_bounds__(256) void k3_gram(
    const float* __restrict__ qdw, const float* __restrict__ kdw,
    float* __restrict__ G, float* __restrict__ sq, float* __restrict__ sk)
{
    __shared__ float Qs[48 * 68];
    __shared__ float Ks[48 * 68];
    int slab = blockIdx.x;
    int h = blockIdx.y, b = blockIdx.z;
    const float* qbase = qdw + ((size_t)b * CC + h * CHD) * HW + slab * 1024;
    const float* kbase = kdw + ((size_t)b * CC + h * CHD) * HW + slab * 1024;
    int tid = threadIdx.x;
    int dx = tid & 15, cy = tid >> 4;
    float g00=0,g01=0,g02=0,g10=0,g11=0,g12=0,g20=0,g21=0,g22=0;
    float aq = 0, ak = 0;
    for (int ch = 0; ch < 16; ch++) {
        #pragma unroll
        for (int i = 0; i < 6; i++) {
            int idx = i * 256 + tid;        // 0..1535 ; 768 per matrix
            int mat = i / 3;                 // 768 = 3*256 so boundary aligns
            int rem = idx - mat * 768;
            int r = rem >> 4, cf = rem & 15;
            const float* srcb = mat ? kbase : qbase;
            float4 v = *(const float4*)(srcb + (size_t)r * HW + ch * 64 + cf * 4);
            float* dsts = mat ? Ks : Qs;
            *(float4*)(dsts + r * 68 + cf * 4) = v;
        }
        __syncthreads();
        #pragma unroll 4
        for (int n = 0; n < 64; n++) {
            float q0 = Qs[(cy*3+0)*68 + n];
            float q1 = Qs[(cy*3+1)*68 + n];
            float q2 = Qs[(cy*3+2)*68 + n];
            float k0 = Ks[(dx*3+0)*68 + n];
            float k1 = Ks[(dx*3+1)*68 + n];
            float k2 = Ks[(dx*3+2)*68 + n];
            g00 += q0*k0; g01 += q0*k1; g02 += q0*k2;
            g10 += q1*k0; g11 += q1*k1; g12 += q1*k2;
            g20 += q2*k0; g21 += q2*k1; g22 += q2*k2;
        }
        if (tid < 96) {
            const float* row = (tid < 48) ? (Qs + tid * 68) : (Ks + (tid - 48) * 68);
            float s = 0;
            #pragma unroll 8
            for (int n = 0; n < 64; n++) { float v = row[n]; s += v * v; }
            if (tid < 48) aq += s; else ak += s;
        }
        __syncthreads();
    }
    float* Gb = G + (size_t)(b * HEADS + h) * CHD * CHD;
    atomicAdd(&Gb[(cy*3+0)*CHD + dx*3+0], g00);
    atomicAdd(&Gb[(cy*3+0)*CHD + dx*3+1], g01);
    atomicAdd(&Gb[(cy*3+0)*CHD + dx*3+2], g02);
    atomicAdd(&Gb[(cy*3+1)*CHD + dx*3+0], g10);
    atomicAdd(&Gb[(cy*3+1)*CHD + dx*3+1], g11);
    atomicAdd(&Gb[(cy*3+1)*CHD + dx*3+2], g12);
    atomicAdd(&Gb[(cy*3+2)*CHD + dx*3+0], g20);
    atomicAdd(&Gb[(cy*3+2)*CHD + dx*3+1], g21);
    atomicAdd(&Gb[(cy*3+2)*CHD + dx*3+2], g22);
    if (tid < 48)      atomicAdd(&sq[b * CC + h * CHD + tid], aq);
    else if (tid < 96) atomicAdd(&sk[b * CC + h * CHD + tid - 48], ak);
}

// ---- K4: attn = relu(G * temp / (|q||k|)); MT[b][h*48+d][o] = sum_c wproj[o][h*48+c]*attn[c][d]
// grid (HEADS, B), block 256
__global__ __launch_bounds__(256) void k4_compose(
    const float* __restrict__ G, const float* __restrict__ sq, const float* __restrict__ sk,
    const float* __restrict__ temp, const float* __restrict__ wproj,
    float* __restrict__ MT)
{
    __shared__ float attnS[CHD * CHD];   // 2304 f
    __shared__ float wS[CC * CHD];       // 9216 f
    int h = blockIdx.x, b = blockIdx.y;
    int tid = threadIdx.x;
    float tv = temp[h];
    const float* Gb = G + (size_t)(b * HEADS + h) * CHD * CHD;
    const float* sqb = sq + b * CC + h * CHD;
    const float* skb = sk + b * CC + h * CHD;
    #pragma unroll
    for (int i = 0; i < 9; i++) {
        int idx = i * 256 + tid;            // 2304 exactly
        int c = idx / CHD, d = idx % CHD;
        float nq = fmaxf(sqrtf(sqb[c]), 1e-12f);
        float nk = fmaxf(sqrtf(skb[d]), 1e-12f);
        float v = Gb[idx] * tv / (nq * nk);
        attnS[idx] = fmaxf(v, 0.f);
    }
    #pragma unroll
    for (int i = 0; i < 36; i++) {
        int idx = i * 256 + tid;            // 9216 exactly
        int o = idx / CHD, c2 = idx % CHD;
        wS[idx] = wproj[o * CC + h * CHD + c2];
    }
    __syncthreads();
    float* MTb = MT + (size_t)b * CC * CC;
    #pragma unroll
    for (int i = 0; i < 36; i++) {
        int idx = i * 256 + tid;
        int o = idx / CHD, d = idx % CHD;
        float s = 0;
        #pragma unroll 8
        for (int c2 = 0; c2 < CHD; c2++)
            s += wS[o * CHD + c2] * attnS[c2 * CHD + d];
        MTb[(h * CHD + d) * CC + o] = s;
    }
}

extern "C" void kernel_launch(void* const* d_in, const int* in_sizes, int n_in,
                              void* d_out, int out_size, void* d_ws, size_t ws_size,
                              hipStream_t stream)
{
    const float* x      = (const float*)d_in[0];
    const float* w_qkv  = (const float*)d_in[1];
    const float* w_dw   = (const float*)d_in[2];
    const float* w_proj = (const float*)d_in[3];
    const float* temp   = (const float*)d_in[4];
    float* out = (float*)d_out;
    float* ws  = (float*)d_ws;

    // small tensors first (~1.93 MB), then one big buffer A (100.7 MB).
    float* wT = ws;                                   // 110,592 f
    float* G  = wT + (size_t)CC * C3;                 // 73,728 f
    float* sq = G  + (size_t)BB * HEADS * CHD * CHD;  // 1,536 f
    float* sk = sq + (size_t)BB * CC;                 // 1,536 f
    float* MT = sk + (size_t)BB * CC;                 // 294,912 f
    float* A  = MT + (size_t)BB * CC * CC;            // 25,165,824 f
    // total: 25,648,128 floats = 102.6 MB

    // zero the atomic accumulators (G, sq, sk contiguous)
    hipMemsetAsync(G, 0, (size_t)(BB * HEADS * CHD * CHD + 2 * BB * CC) * sizeof(float), stream);

    k0_transpose<<<dim3((CC * C3 + 255) / 256), 256, 0, stream>>>(w_qkv, wT);

    const dim3 ggrid(HW / 256, CC / 64, BB);

    // q = Wq @ x -> d_out ; depthwise in place
    gemm_ko<<<ggrid, 256, 0, stream>>>(wT + 0, 0L, C3, x, (long)CC * HW, out, (long)CC * HW);
    k_dw_ip<<<dim3(BB * CC), 256, 0, stream>>>(out, w_dw, 0);

    // k = Wk @ x -> A ; depthwise in place
    gemm_ko<<<ggrid, 256, 0, stream>>>(wT + CC, 0L, C3, x, (long)CC * HW, A, (long)CC * HW);
    k_dw_ip<<<dim3(BB * CC), 256, 0, stream>>>(A, w_dw, CC);

    // Gram + channel norms (q_dw = d_out, k_dw = A)
    k3_gram<<<dim3(16, HEADS, BB), 256, 0, stream>>>(out, A, G, sq, sk);

    // v = Wv @ x -> A (k_dw dead) ; depthwise in place
    gemm_ko<<<ggrid, 256, 0, stream>>>(wT + 2 * CC, 0L, C3, x, (long)CC * HW, A, (long)CC * HW);
    k_dw_ip<<<dim3(BB * CC), 256, 0, stream>>>(A, w_dw, 2 * CC);

    // attn + fold projection into per-batch M (k-major)
    k4_compose<<<dim3(HEADS, BB), 256, 0, stream>>>(G, sq, sk, temp, w_proj, MT);

    // out = M_b @ v_dw  (reads A, writes d_out; q_dw dead)
    gemm_ko<<<ggrid, 256, 0, stream>>>(MT, (long)CC * CC, CC, A, (long)CC * HW, out, (long)CC * HW);
}

// Round 4
// 445.469 us; speedup vs baseline: 1.8110x; 1.8110x over previous
//
#include <hip/hip_runtime.h>

#define BB 8
#define CC 192
#define C3 576
#define HW 16384
#define HEADS 4
#define CHD 48
#define NPLANE (BB*CC)

typedef short s8v __attribute__((ext_vector_type(8)));
typedef float f16v __attribute__((ext_vector_type(16)));
typedef float f4v __attribute__((ext_vector_type(4)));

__device__ __forceinline__ ushort bfu(float f) {
    union { float f; unsigned u; } c; c.f = f;
    unsigned u = c.u + 0x7FFFu + ((c.u >> 16) & 1u);
    return (ushort)(u >> 16);
}
__device__ __forceinline__ float ubf(ushort u) {
    union { unsigned u; float f; } c; c.u = ((unsigned)u) << 16;
    return c.f;
}

// ---- convert w_qkv fp32 [576][192] -> bf16 same layout ([o][k], k-contig = A-layout)
__global__ void kw_cvt(const float* __restrict__ w, ushort* __restrict__ wbf) {
    int idx = blockIdx.x * 256 + threadIdx.x;
    if (idx < C3 * CC) wbf[idx] = bfu(w[idx]);
}

// ---- MFMA GEMM. MODE0: qkv (A=wbf[576][192], B=x fp32 -> bf16 out split qk/vb)
//      MODE1: final (A=Mbf[b][192][192], B=vb bf16 -> fp32 out)
// block 256 = 4 waves (2M x 2N), tile BM=192 BN=128, K=192, KSTEP=16
template<int MODE>
__global__ __launch_bounds__(256) void gemm_mfma(
    const ushort* __restrict__ A,
    const float* __restrict__ Xf,
    const ushort* __restrict__ Xh,
    ushort* __restrict__ qk, ushort* __restrict__ vb,
    float* __restrict__ outf)
{
    __shared__ ushort As[2 * 192 * 8];   // [kg][o][8k]  (frag reads lane-contiguous)
    __shared__ ushort Xs[2 * 128 * 8];   // [kg][p][8k]
    int lin = blockIdx.x, sec, pt, b;
    if (MODE == 0) {
        int logical = (lin & 7) * 384 + (lin >> 3);   // XCD-contiguous chunks (3072%8==0)
        sec = logical % 3;
        int pb = logical / 3;
        pt = pb & 127; b = pb >> 7;
    } else { sec = 0; pt = lin & 127; b = lin >> 7; }
    const int t = threadIdx.x, lane = t & 63, w = t >> 6;
    const int wr = w >> 1, wc = w & 1;
    const int pbase = pt * 128;
    const ushort* Ab = A + (MODE == 0 ? (size_t)sec * CC * CC : (size_t)b * CC * CC);

    f16v acc[3][2];
    #pragma unroll
    for (int mt = 0; mt < 3; mt++)
        #pragma unroll
        for (int nt = 0; nt < 2; nt++)
            #pragma unroll
            for (int i = 0; i < 16; i++) acc[mt][nt][i] = 0.f;

    const int kgs = t >> 7, ps = t & 127;   // staging role

    for (int ks = 0; ks < 12; ks++) {
        const int k0 = ks * 16;
        if (t < 192) {   // stage A: row o=t, 16 k as 2x int4
            const ushort* s = Ab + (size_t)t * CC + k0;
            *(int4*)&As[(size_t)t * 8] = *(const int4*)s;
            *(int4*)&As[(size_t)(192 + t) * 8] = *(const int4*)(s + 8);
        }
        {   // stage B: thread owns (kg, p): 8 coalesced scalar loads -> packed b128
            unsigned wb4[4];
            if (MODE == 0) {
                const float* s = Xf + ((size_t)b * CC + k0 + kgs * 8) * HW + pbase + ps;
                float f[8];
                #pragma unroll
                for (int j = 0; j < 8; j++) f[j] = s[(size_t)j * HW];
                #pragma unroll
                for (int j = 0; j < 4; j++)
                    wb4[j] = (unsigned)bfu(f[2*j]) | ((unsigned)bfu(f[2*j+1]) << 16);
            } else {
                const ushort* s = Xh + ((size_t)b * CC + k0 + kgs * 8) * HW + pbase + ps;
                ushort u[8];
                #pragma unroll
                for (int j = 0; j < 8; j++) u[j] = s[(size_t)j * HW];
                #pragma unroll
                for (int j = 0; j < 4; j++)
                    wb4[j] = (unsigned)u[2*j] | ((unsigned)u[2*j+1] << 16);
            }
            *(int4*)&Xs[(size_t)(kgs * 128 + ps) * 8] = *(const int4*)wb4;
        }
        __syncthreads();
        const int ll = lane & 31, kg = lane >> 5;
        s8v af[3], bfv[2];
        #pragma unroll
        for (int mt = 0; mt < 3; mt++)
            af[mt] = *(const s8v*)&As[(size_t)(kg * 192 + wr * 96 + mt * 32 + ll) * 8];
        #pragma unroll
        for (int nt = 0; nt < 2; nt++)
            bfv[nt] = *(const s8v*)&Xs[(size_t)(kg * 128 + wc * 64 + nt * 32 + ll) * 8];
        #pragma unroll
        for (int mt = 0; mt < 3; mt++)
            #pragma unroll
            for (int nt = 0; nt < 2; nt++)
                acc[mt][nt] = __builtin_amdgcn_mfma_f32_32x32x16_bf16(af[mt], bfv[nt], acc[mt][nt], 0, 0, 0);
        __syncthreads();
    }

    const int ll = lane & 31, kg = lane >> 5;
    if (MODE == 0) {
        ushort* ob = sec < 2 ? qk + (size_t)(sec * BB + b) * CC * HW
                             : vb + (size_t)b * CC * HW;
        #pragma unroll
        for (int mt = 0; mt < 3; mt++)
            #pragma unroll
            for (int nt = 0; nt < 2; nt++)
                #pragma unroll
                for (int r = 0; r < 16; r++) {
                    int o = wr * 96 + mt * 32 + (r & 3) + 8 * (r >> 2) + 4 * kg;
                    int p = pbase + wc * 64 + nt * 32 + ll;
                    ob[(size_t)o * HW + p] = bfu(acc[mt][nt][r]);
                }
    } else {
        #pragma unroll
        for (int mt = 0; mt < 3; mt++)
            #pragma unroll
            for (int nt = 0; nt < 2; nt++)
                #pragma unroll
                for (int r = 0; r < 16; r++) {
                    int o = wr * 96 + mt * 32 + (r & 3) + 8 * (r >> 2) + 4 * kg;
                    int p = pbase + wc * 64 + nt * 32 + ll;
                    outf[((size_t)b * CC + o) * HW + p] = acc[mt][nt][r];
                }
    }
}

// ---- in-place depthwise 3x3 on bf16 planes + exact fp32 sum-of-squares for q/k
__global__ __launch_bounds__(256) void k_dw_bf(
    ushort* __restrict__ qk, ushort* __restrict__ vb,
    const float* __restrict__ wdw, float* __restrict__ sq, float* __restrict__ sk)
{
    __shared__ ushort rows[10][128];
    __shared__ float red[4];
    int pid = blockIdx.x;
    int sec = pid / NPLANE, rem = pid % NPLANE;
    int b = rem / CC, c = rem % CC;
    ushort* p = sec < 2 ? qk + ((size_t)(sec * BB + b) * CC + c) * HW
                        : vb + ((size_t)b * CC + c) * HW;
    const float* wc9 = wdw + (size_t)(sec * CC + c) * 9;
    float w0=wc9[0],w1=wc9[1],w2=wc9[2],w3=wc9[3],w4=wc9[4],w5=wc9[5],w6=wc9[6],w7=wc9[7],w8=wc9[8];
    const int t = threadIdx.x, lr = t >> 5, lx = (t & 31) * 4;
    float ss = 0.f;
    if (t < 32) ((ushort4*)rows[0])[t] = ((const ushort4*)p)[t];
    __syncthreads();
    for (int y0 = 0; y0 < 128; y0 += 8) {
        int ry = y0 + 1 + lr;
        if (ry < 128) *(ushort4*)&rows[ry % 10][lx] = *(const ushort4*)(p + (size_t)ry * 128 + lx);
        __syncthreads();
        const int oy = y0 + lr;
        float a0=0,a1=0,a2=0,a3=0;
        if (oy >= 1) {
            const ushort* rw = rows[(oy - 1) % 10];
            float m0=ubf(rw[lx]),m1=ubf(rw[lx+1]),m2=ubf(rw[lx+2]),m3=ubf(rw[lx+3]);
            float lf = lx ? ubf(rw[lx-1]) : 0.f, rt = (lx < 124) ? ubf(rw[lx+4]) : 0.f;
            a0 += w0*lf + w1*m0 + w2*m1;  a1 += w0*m0 + w1*m1 + w2*m2;
            a2 += w0*m1 + w1*m2 + w2*m3;  a3 += w0*m2 + w1*m3 + w2*rt;
        }
        {
            const ushort* rw = rows[oy % 10];
            float m0=ubf(rw[lx]),m1=ubf(rw[lx+1]),m2=ubf(rw[lx+2]),m3=ubf(rw[lx+3]);
            float lf = lx ? ubf(rw[lx-1]) : 0.f, rt = (lx < 124) ? ubf(rw[lx+4]) : 0.f;
            a0 += w3*lf + w4*m0 + w5*m1;  a1 += w3*m0 + w4*m1 + w5*m2;
            a2 += w3*m1 + w4*m2 + w5*m3;  a3 += w3*m2 + w4*m3 + w5*rt;
        }
        if (oy + 1 < 128) {
            const ushort* rw = rows[(oy + 1) % 10];
            float m0=ubf(rw[lx]),m1=ubf(rw[lx+1]),m2=ubf(rw[lx+2]),m3=ubf(rw[lx+3]);
            float lf = lx ? ubf(rw[lx-1]) : 0.f, rt = (lx < 124) ? ubf(rw[lx+4]) : 0.f;
            a0 += w6*lf + w7*m0 + w8*m1;  a1 += w6*m0 + w7*m1 + w8*m2;
            a2 += w6*m1 + w7*m2 + w8*m3;  a3 += w6*m2 + w7*m3 + w8*rt;
        }
        ss += a0*a0 + a1*a1 + a2*a2 + a3*a3;
        __syncthreads();
        ushort4 o4; o4.x = bfu(a0); o4.y = bfu(a1); o4.z = bfu(a2); o4.w = bfu(a3);
        *(ushort4*)(p + (size_t)oy * 128 + lx) = o4;
    }
    if (sec < 2) {
        for (int off = 32; off; off >>= 1) ss += __shfl_down(ss, off);
        if ((t & 63) == 0) red[t >> 6] = ss;
        __syncthreads();
        if (t == 0) (sec == 0 ? sq : sk)[b * CC + c] = red[0] + red[1] + red[2] + red[3];
    }
}

// ---- Gram via MFMA 16x16x32, operands direct from global (n-contiguous per lane)
__global__ __launch_bounds__(256) void k_gram(
    const ushort* __restrict__ qk, float* __restrict__ G)
{
    int slab = blockIdx.x, h = blockIdx.y, b = blockIdx.z;
    const int t = threadIdx.x, lane = t & 63, w = t >> 6;
    const ushort* qb = qk + ((size_t)b * CC + h * CHD) * HW;
    const ushort* kb = qk + ((size_t)(BB + b) * CC + h * CHD) * HW;
    const int ll = lane & 15, lh = lane >> 4;
    f4v acc[3][3];
    #pragma unroll
    for (int i = 0; i < 3; i++)
        #pragma unroll
        for (int j = 0; j < 3; j++)
            #pragma unroll
            for (int r = 0; r < 4; r++) acc[i][j][r] = 0.f;
    const int nbase = slab * 1024 + w * 256 + lh * 8;
    for (int s = 0; s < 8; s++) {
        const int n = nbase + s * 32;
        s8v aq[3], bk[3];
        #pragma unroll
        for (int mt = 0; mt < 3; mt++)
            aq[mt] = *(const s8v*)(qb + (size_t)(mt * 16 + ll) * HW + n);
        #pragma unroll
        for (int mt = 0; mt < 3; mt++)
            bk[mt] = *(const s8v*)(kb + (size_t)(mt * 16 + ll) * HW + n);
        #pragma unroll
        for (int i = 0; i < 3; i++)
            #pragma unroll
            for (int j = 0; j < 3; j++)
                acc[i][j] = __builtin_amdgcn_mfma_f32_16x16x32_bf16(aq[i], bk[j], acc[i][j], 0, 0, 0);
    }
    float* Gb = G + (size_t)(b * HEADS + h) * CHD * CHD;
    #pragma unroll
    for (int i = 0; i < 3; i++)
        #pragma unroll
        for (int j = 0; j < 3; j++)
            #pragma unroll
            for (int r = 0; r < 4; r++) {
                int c = i * 16 + lh * 4 + r, d = j * 16 + ll;
                atomicAdd(&Gb[c * CHD + d], acc[i][j][r]);
            }
}

// ---- attn = relu(G*temp/(|q||k|)); Mbf[b][o][h*48+d] = sum_c wproj[o][h*48+c]*attn[c][d] (bf16)
__global__ __launch_bounds__(256) void k_compose(
    const float* __restrict__ G, const float* __restrict__ sq, const float* __restrict__ sk,
    const float* __restrict__ temp, const float* __restrict__ wproj,
    ushort* __restrict__ Mbf)
{
    __shared__ float attnS[CHD * CHD];
    __shared__ float wS[CC * CHD];
    int h = blockIdx.x, b = blockIdx.y, t = threadIdx.x;
    float tv = temp[h];
    const float* Gb = G + (size_t)(b * HEADS + h) * CHD * CHD;
    const float* sqb = sq + b * CC + h * CHD;
    const float* skb = sk + b * CC + h * CHD;
    #pragma unroll
    for (int i = 0; i < 9; i++) {
        int idx = i * 256 + t;
        int c = idx / CHD, d = idx % CHD;
        float nq = fmaxf(sqrtf(sqb[c]), 1e-12f);
        float nk = fmaxf(sqrtf(skb[d]), 1e-12f);
        float v = Gb[idx] * tv / (nq * nk);
        attnS[idx] = fmaxf(v, 0.f);
    }
    #pragma unroll
    for (int i = 0; i < 36; i++) {
        int idx = i * 256 + t;
        wS[idx] = wproj[(idx / CHD) * CC + h * CHD + idx % CHD];
    }
    __syncthreads();
    ushort* Mb = Mbf + (size_t)b * CC * CC;
    #pragma unroll
    for (int i = 0; i < 36; i++) {
        int idx = i * 256 + t;
        int o = idx / CHD, d = idx % CHD;
        float s = 0.f;
        #pragma unroll 8
        for (int c2 = 0; c2 < CHD; c2++)
            s += wS[o * CHD + c2] * attnS[c2 * CHD + d];
        Mb[o * CC + h * CHD + d] = bfu(s);
    }
}

extern "C" void kernel_launch(void* const* d_in, const int* in_sizes, int n_in,
                              void* d_out, int out_size, void* d_ws, size_t ws_size,
                              hipStream_t stream)
{
    const float* x      = (const float*)d_in[0];
    const float* w_qkv  = (const float*)d_in[1];
    const float* w_dw   = (const float*)d_in[2];
    const float* w_proj = (const float*)d_in[3];
    const float* temp   = (const float*)d_in[4];
    float* out = (float*)d_out;
    float* ws  = (float*)d_ws;

    // d_out doubles as the q_bf/k_bf store: 2 * 8*192*16384 bf16 = exactly out_size*4 bytes
    ushort* qk = (ushort*)d_out;

    // ws layout (~51.5 MB total)
    float* G  = ws;                                    // 32*48*48 = 73728 f
    float* sq = G  + (size_t)BB * HEADS * CHD * CHD;   // 1536 f
    float* sk = sq + (size_t)BB * CC;                  // 1536 f
    ushort* wbf  = (ushort*)(sk + (size_t)BB * CC);    // 110592 u16
    ushort* Mbf  = wbf + (size_t)C3 * CC;              // 294912 u16
    ushort* vbuf = Mbf + (size_t)BB * CC * CC;         // 25165824 u16

    kw_cvt<<<dim3((C3 * CC + 255) / 256), 256, 0, stream>>>(w_qkv, wbf);
    hipMemsetAsync(G, 0, (size_t)BB * HEADS * CHD * CHD * sizeof(float), stream);

    // fused qkv GEMM (bf16 MFMA): q,k -> d_out (bf16), v -> vbuf
    gemm_mfma<0><<<dim3(3072), 256, 0, stream>>>(wbf, x, nullptr, qk, vbuf, nullptr);

    // depthwise 3x3 in place on all 576*8 planes + exact sum-of-squares for q/k
    k_dw_bf<<<dim3(3 * NPLANE), 256, 0, stream>>>(qk, vbuf, w_dw, sq, sk);

    // channel Gram per (b,head) via MFMA
    k_gram<<<dim3(16, HEADS, BB), 256, 0, stream>>>(qk, G);

    // attn + fold output projection into per-batch M (bf16, [o][c] layout)
    k_compose<<<dim3(HEADS, BB), 256, 0, stream>>>(G, sq, sk, temp, w_proj, Mbf);

    // out = M_b @ v_dw (fp32 out, overwrites q/k region of d_out)
    gemm_mfma<1><<<dim3(1024), 256, 0, stream>>>(Mbf, nullptr, vbuf, nullptr, nullptr, out);
}

// Round 6
// 425.805 us; speedup vs baseline: 1.8946x; 1.0462x over previous
//
#include <hip/hip_runtime.h>

#define BB 8
#define CC 192
#define C3 576
#define HW 16384
#define HEADS 4
#define CHD 48
#define NPLANE (BB*CC)

typedef short s8v __attribute__((ext_vector_type(8)));
typedef float f16v __attribute__((ext_vector_type(16)));
typedef float f4v __attribute__((ext_vector_type(4)));

__device__ __forceinline__ ushort bfu(float f) {
    union { float f; unsigned u; } c; c.f = f;
    unsigned u = c.u + 0x7FFFu + ((c.u >> 16) & 1u);
    return (ushort)(u >> 16);
}
__device__ __forceinline__ float ubf(ushort u) {
    union { unsigned u; float f; } c; c.u = ((unsigned)u) << 16;
    return c.f;
}

// ---- convert w_qkv fp32 [576][192] -> bf16 same layout ([o][k], k-contig = A-layout)
__global__ void kw_cvt(const float* __restrict__ w, ushort* __restrict__ wbf) {
    int idx = blockIdx.x * 256 + threadIdx.x;
    if (idx < C3 * CC) wbf[idx] = bfu(w[idx]);
}

// ---- transpose to MFMA-B layout: src [b][c][p] (fp32 or bf16) -> T [b][c/8][p][8c] bf16
// grid (8, 24, 16), block 256; thread owns 4 consecutive p for one 8-c group.
template<int SRC>
__global__ __launch_bounds__(256) void k_trans(
    const float* __restrict__ xf, const ushort* __restrict__ xh,
    ushort* __restrict__ T)
{
    const int b = blockIdx.x, cg = blockIdx.y;
    const int p = blockIdx.z * 1024 + threadIdx.x * 4;
    float a[8][4];
    #pragma unroll
    for (int c = 0; c < 8; c++) {
        if (SRC == 0) {
            *(float4*)a[c] = *(const float4*)(xf + ((size_t)(b * CC + cg * 8 + c) * HW + p));
        } else {
            ushort4 u = *(const ushort4*)(xh + ((size_t)(b * CC + cg * 8 + c) * HW + p));
            a[c][0] = ubf(u.x); a[c][1] = ubf(u.y); a[c][2] = ubf(u.z); a[c][3] = ubf(u.w);
        }
    }
    #pragma unroll
    for (int j = 0; j < 4; j++) {
        unsigned wp[4];
        #pragma unroll
        for (int i = 0; i < 4; i++)
            wp[i] = (unsigned)bfu(a[2*i][j]) | ((unsigned)bfu(a[2*i+1][j]) << 16);
        *(uint4*)(T + ((size_t)(b * 24 + cg) * HW + p + j) * 8) = *(const uint4*)wp;
    }
}

// ---- LDS-free MFMA GEMM. MODE0: A=wbf (3 sections), B=xT -> q,k,v bf16 planes
//      MODE1: A=Mbf[b], B=vT -> fp32 out. block 256 = 4 waves (2M x 2N), BM=192 BN=128 K=192
template<int MODE>
__global__ __launch_bounds__(256) void gemm_mfma(
    const ushort* __restrict__ A,
    const ushort* __restrict__ BT,
    ushort* __restrict__ qk, ushort* __restrict__ vpl,
    float* __restrict__ outf)
{
    __shared__ ushort Rep[MODE == 0 ? 192 * 136 : 8];
    int lin = blockIdx.x, sec, pt, b;
    if (MODE == 0) {
        int logical = (lin & 7) * 384 + (lin >> 3);   // XCD-contiguous (3072/8=384)
        sec = logical % 3;
        int pb = logical / 3;
        pt = pb & 127; b = pb >> 7;
    } else {
        int logical = (lin & 7) * 128 + (lin >> 3);   // each XCD owns one batch
        sec = 0; b = logical >> 7; pt = logical & 127;
    }
    const int t = threadIdx.x, lane = t & 63, w = t >> 6;
    const int wr = w >> 1, wc = w & 1;
    const int ll = lane & 31, kg = lane >> 5;
    const int pbase = pt * 128;
    const ushort* Ab = A + (size_t)(MODE == 0 ? sec : b) * CC * CC;
    const ushort* Bb = BT + (size_t)b * 24 * HW * 8;

    f16v acc[3][2];
    #pragma unroll
    for (int mt = 0; mt < 3; mt++)
        #pragma unroll
        for (int nt = 0; nt < 2; nt++)
            #pragma unroll
            for (int i = 0; i < 16; i++) acc[mt][nt][i] = 0.f;

    #pragma unroll 4
    for (int ks = 0; ks < 12; ks++) {
        s8v af[3], bfr[2];
        #pragma unroll
        for (int mt = 0; mt < 3; mt++)
            af[mt] = *(const s8v*)(Ab + (size_t)(wr * 96 + mt * 32 + ll) * CC + ks * 16 + kg * 8);
        #pragma unroll
        for (int nt = 0; nt < 2; nt++)
            bfr[nt] = *(const s8v*)(Bb + ((size_t)(ks * 2 + kg) * HW + pbase + wc * 64 + nt * 32 + ll) * 8);
        #pragma unroll
        for (int mt = 0; mt < 3; mt++)
            #pragma unroll
            for (int nt = 0; nt < 2; nt++)
                acc[mt][nt] = __builtin_amdgcn_mfma_f32_32x32x16_bf16(af[mt], bfr[nt], acc[mt][nt], 0, 0, 0);
    }

    if (MODE == 0) {
        // scatter acc -> LDS [o][p] (pad 136), then coalesced 16B stores
        #pragma unroll
        for (int mt = 0; mt < 3; mt++)
            #pragma unroll
            for (int nt = 0; nt < 2; nt++)
                #pragma unroll
                for (int g = 0; g < 4; g++)
                    #pragma unroll
                    for (int j = 0; j < 4; j++)
                        Rep[(wr * 96 + mt * 32 + 8 * g + 4 * kg + j) * 136
                            + wc * 64 + nt * 32 + ll] = bfu(acc[mt][nt][4 * g + j]);
        __syncthreads();
        ushort* ob = (sec == 2) ? vpl + (size_t)b * CC * HW
                                : qk + (size_t)(sec * BB + b) * CC * HW;
        #pragma unroll
        for (int i = 0; i < 12; i++) {
            int idx = i * 256 + t;           // 3072 chunks of 8 ushorts
            int row = idx >> 4, c8 = idx & 15;
            int4 vv = *(const int4*)&Rep[row * 136 + c8 * 8];
            *(int4*)(ob + (size_t)row * HW + pbase + c8 * 8) = vv;
        }
    } else {
        #pragma unroll
        for (int mt = 0; mt < 3; mt++)
            #pragma unroll
            for (int nt = 0; nt < 2; nt++)
                #pragma unroll
                for (int r = 0; r < 16; r++) {
                    int o = wr * 96 + mt * 32 + (r & 3) + 8 * (r >> 2) + 4 * kg;
                    int p = pbase + wc * 64 + nt * 32 + ll;
                    outf[((size_t)b * CC + o) * HW + p] = acc[mt][nt][r];
                }
    }
}

// ---- in-place depthwise 3x3 on bf16 planes + exact fp32 sum-of-squares for q/k
__global__ __launch_bounds__(256) void k_dw_bf(
    ushort* __restrict__ qk, ushort* __restrict__ vb,
    const float* __restrict__ wdw, float* __restrict__ sq, float* __restrict__ sk)
{
    __shared__ ushort rows[10][128];
    __shared__ float red[4];
    int pid = blockIdx.x;
    int sec = pid / NPLANE, rem = pid % NPLANE;
    int b = rem / CC, c = rem % CC;
    ushort* p = sec < 2 ? qk + ((size_t)(sec * BB + b) * CC + c) * HW
                        : vb + ((size_t)b * CC + c) * HW;
    const float* wc9 = wdw + (size_t)(sec * CC + c) * 9;
    float w0=wc9[0],w1=wc9[1],w2=wc9[2],w3=wc9[3],w4=wc9[4],w5=wc9[5],w6=wc9[6],w7=wc9[7],w8=wc9[8];
    const int t = threadIdx.x, lr = t >> 5, lx = (t & 31) * 4;
    float ss = 0.f;
    if (t < 32) ((ushort4*)rows[0])[t] = ((const ushort4*)p)[t];
    __syncthreads();
    for (int y0 = 0; y0 < 128; y0 += 8) {
        int ry = y0 + 1 + lr;
        if (ry < 128) *(ushort4*)&rows[ry % 10][lx] = *(const ushort4*)(p + (size_t)ry * 128 + lx);
        __syncthreads();
        const int oy = y0 + lr;
        float a0=0,a1=0,a2=0,a3=0;
        if (oy >= 1) {
            const ushort* rw = rows[(oy - 1) % 10];
            float m0=ubf(rw[lx]),m1=ubf(rw[lx+1]),m2=ubf(rw[lx+2]),m3=ubf(rw[lx+3]);
            float lf = lx ? ubf(rw[lx-1]) : 0.f, rt = (lx < 124) ? ubf(rw[lx+4]) : 0.f;
            a0 += w0*lf + w1*m0 + w2*m1;  a1 += w0*m0 + w1*m1 + w2*m2;
            a2 += w0*m1 + w1*m2 + w2*m3;  a3 += w0*m2 + w1*m3 + w2*rt;
        }
        {
            const ushort* rw = rows[oy % 10];
            float m0=ubf(rw[lx]),m1=ubf(rw[lx+1]),m2=ubf(rw[lx+2]),m3=ubf(rw[lx+3]);
            float lf = lx ? ubf(rw[lx-1]) : 0.f, rt = (lx < 124) ? ubf(rw[lx+4]) : 0.f;
            a0 += w3*lf + w4*m0 + w5*m1;  a1 += w3*m0 + w4*m1 + w5*m2;
            a2 += w3*m1 + w4*m2 + w5*m3;  a3 += w3*m2 + w4*m3 + w5*rt;
        }
        if (oy + 1 < 128) {
            const ushort* rw = rows[(oy + 1) % 10];
            float m0=ubf(rw[lx]),m1=ubf(rw[lx+1]),m2=ubf(rw[lx+2]),m3=ubf(rw[lx+3]);
            float lf = lx ? ubf(rw[lx-1]) : 0.f, rt = (lx < 124) ? ubf(rw[lx+4]) : 0.f;
            a0 += w6*lf + w7*m0 + w8*m1;  a1 += w6*m0 + w7*m1 + w8*m2;
            a2 += w6*m1 + w7*m2 + w8*m3;  a3 += w6*m2 + w7*m3 + w8*rt;
        }
        ss += a0*a0 + a1*a1 + a2*a2 + a3*a3;
        __syncthreads();
        ushort4 o4; o4.x = bfu(a0); o4.y = bfu(a1); o4.z = bfu(a2); o4.w = bfu(a3);
        *(ushort4*)(p + (size_t)oy * 128 + lx) = o4;
    }
    if (sec < 2) {
        for (int off = 32; off; off >>= 1) ss += __shfl_down(ss, off);
        if ((t & 63) == 0) red[t >> 6] = ss;
        __syncthreads();
        if (t == 0) (sec == 0 ? sq : sk)[b * CC + c] = red[0] + red[1] + red[2] + red[3];
    }
}

// ---- Gram via MFMA 16x16x32, operands direct from global (n-contiguous per lane)
__global__ __launch_bounds__(256) void k_gram(
    const ushort* __restrict__ qk, float* __restrict__ G)
{
    int slab = blockIdx.x, h = blockIdx.y, b = blockIdx.z;
    const int t = threadIdx.x, lane = t & 63, w = t >> 6;
    const ushort* qb = qk + ((size_t)b * CC + h * CHD) * HW;
    const ushort* kb = qk + ((size_t)(BB + b) * CC + h * CHD) * HW;
    const int ll = lane & 15, lh = lane >> 4;
    f4v acc[3][3];
    #pragma unroll
    for (int i = 0; i < 3; i++)
        #pragma unroll
        for (int j = 0; j < 3; j++)
            #pragma unroll
            for (int r = 0; r < 4; r++) acc[i][j][r] = 0.f;
    const int nbase = slab * 1024 + w * 256 + lh * 8;
    for (int s = 0; s < 8; s++) {
        const int n = nbase + s * 32;
        s8v aq[3], bk[3];
        #pragma unroll
        for (int mt = 0; mt < 3; mt++)
            aq[mt] = *(const s8v*)(qb + (size_t)(mt * 16 + ll) * HW + n);
        #pragma unroll
        for (int mt = 0; mt < 3; mt++)
            bk[mt] = *(const s8v*)(kb + (size_t)(mt * 16 + ll) * HW + n);
        #pragma unroll
        for (int i = 0; i < 3; i++)
            #pragma unroll
            for (int j = 0; j < 3; j++)
                acc[i][j] = __builtin_amdgcn_mfma_f32_16x16x32_bf16(aq[i], bk[j], acc[i][j], 0, 0, 0);
    }
    float* Gb = G + (size_t)(b * HEADS + h) * CHD * CHD;
    #pragma unroll
    for (int i = 0; i < 3; i++)
        #pragma unroll
        for (int j = 0; j < 3; j++)
            #pragma unroll
            for (int r = 0; r < 4; r++) {
                int c = i * 16 + lh * 4 + r, d = j * 16 + ll;
                atomicAdd(&Gb[c * CHD + d], acc[i][j][r]);
            }
}

// ---- attn = relu(G*temp/(|q||k|)); Mbf[b][o][h*48+d] = sum_c wproj[o][h*48+c]*attn[c][d] (bf16)
__global__ __launch_bounds__(256) void k_compose(
    const float* __restrict__ G, const float* __restrict__ sq, const float* __restrict__ sk,
    const float* __restrict__ temp, const float* __restrict__ wproj,
    ushort* __restrict__ Mbf)
{
    __shared__ float attnS[CHD * CHD];
    __shared__ float wS[CC * CHD];
    int h = blockIdx.x, b = blockIdx.y, t = threadIdx.x;
    float tv = temp[h];
    const float* Gb = G + (size_t)(b * HEADS + h) * CHD * CHD;
    const float* sqb = sq + b * CC + h * CHD;
    const float* skb = sk + b * CC + h * CHD;
    #pragma unroll
    for (int i = 0; i < 9; i++) {
        int idx = i * 256 + t;
        int c = idx / CHD, d = idx % CHD;
        float nq = fmaxf(sqrtf(sqb[c]), 1e-12f);
        float nk = fmaxf(sqrtf(skb[d]), 1e-12f);
        float v = Gb[idx] * tv / (nq * nk);
        attnS[idx] = fmaxf(v, 0.f);
    }
    #pragma unroll
    for (int i = 0; i < 36; i++) {
        int idx = i * 256 + t;
        wS[idx] = wproj[(idx / CHD) * CC + h * CHD + idx % CHD];
    }
    __syncthreads();
    ushort* Mb = Mbf + (size_t)b * CC * CC;
    #pragma unroll
    for (int i = 0; i < 36; i++) {
        int idx = i * 256 + t;
        int o = idx / CHD, d = idx % CHD;
        float s = 0.f;
        #pragma unroll 8
        for (int c2 = 0; c2 < CHD; c2++)
            s += wS[o * CHD + c2] * attnS[c2 * CHD + d];
        Mb[o * CC + h * CHD + d] = bfu(s);
    }
}

extern "C" void kernel_launch(void* const* d_in, const int* in_sizes, int n_in,
                              void* d_out, int out_size, void* d_ws, size_t ws_size,
                              hipStream_t stream)
{
    const float* x      = (const float*)d_in[0];
    const float* w_qkv  = (const float*)d_in[1];
    const float* w_dw   = (const float*)d_in[2];
    const float* w_proj = (const float*)d_in[3];
    const float* temp   = (const float*)d_in[4];
    float* out = (float*)d_out;

    // d_out doubles as q_bf/k_bf planes (exactly out_size*4 bytes)
    ushort* qk = (ushort*)d_out;

    // ws layout (~97.1 MB): [xT/vT][v planes][G][sq][sk][wbf][Mbf]
    ushort* xT = (ushort*)d_ws;                        // 25,165,824 u16 (reused as vT)
    ushort* vb = xT + (size_t)BB * CC * HW;            // 25,165,824 u16
    float*  G  = (float*)(vb + (size_t)BB * CC * HW);  // 73,728 f
    float*  sq = G + (size_t)BB * HEADS * CHD * CHD;   // 1,536 f
    float*  sk = sq + (size_t)BB * CC;                 // 1,536 f
    ushort* wbf = (ushort*)(sk + (size_t)BB * CC);     // 110,592 u16
    ushort* Mbf = wbf + (size_t)C3 * CC;               // 294,912 u16

    kw_cvt<<<dim3((C3 * CC + 255) / 256), 256, 0, stream>>>(w_qkv, wbf);
    hipMemsetAsync(G, 0, (size_t)BB * HEADS * CHD * CHD * sizeof(float), stream);

    // x -> xT (bf16, MFMA-B layout)
    k_trans<0><<<dim3(BB, 24, 16), 256, 0, stream>>>(x, nullptr, xT);

    // fused qkv GEMM: q,k -> d_out planes, v -> vb planes
    gemm_mfma<0><<<dim3(3072), 256, 0, stream>>>(wbf, xT, qk, vb, nullptr);

    // depthwise 3x3 in place on all planes + exact sum-of-squares for q/k
    k_dw_bf<<<dim3(3 * NPLANE), 256, 0, stream>>>(qk, vb, w_dw, sq, sk);

    // v planes -> vT (reuses xT slot; xT dead after gemm0)
    k_trans<1><<<dim3(BB, 24, 16), 256, 0, stream>>>(nullptr, vb, xT);

    // channel Gram per (b,head)
    k_gram<<<dim3(16, HEADS, BB), 256, 0, stream>>>(qk, G);

    // attn + fold output projection into per-batch M (bf16)
    k_compose<<<dim3(HEADS, BB), 256, 0, stream>>>(G, sq, sk, temp, w_proj, Mbf);

    // out = M_b @ v_dw (fp32, overwrites q/k region of d_out)
    gemm_mfma<1><<<dim3(1024), 256, 0, stream>>>(Mbf, xT, nullptr, nullptr, out);
}

// Round 8
// 401.233 us; speedup vs baseline: 2.0107x; 1.0612x over previous
//
#include <hip/hip_runtime.h>

#define BB 8
#define CC 192
#define C3 576
#define HW 16384
#define HEADS 4
#define CHD 48
#define NPLANE (BB*CC)

typedef short s8v __attribute__((ext_vector_type(8)));
typedef float f16v __attribute__((ext_vector_type(16)));
typedef float f4v __attribute__((ext_vector_type(4)));

__device__ __forceinline__ ushort bfu(float f) {
    union { float f; unsigned u; } c; c.f = f;
    unsigned u = c.u + 0x7FFFu + ((c.u >> 16) & 1u);
    return (ushort)(u >> 16);
}
__device__ __forceinline__ float ubf(ushort u) {
    union { unsigned u; float f; } c; c.u = ((unsigned)u) << 16;
    return c.f;
}

// ---- convert w_qkv fp32 [576][192] -> bf16 in MFMA A-fragment order:
// wPack[sec][kg16 = k/8][row = o%192][k&7]
__global__ void kw_cvt(const float* __restrict__ w, ushort* __restrict__ wbf) {
    int idx = blockIdx.x * 256 + threadIdx.x;
    if (idx >= C3 * CC) return;
    int o = idx / CC, k = idx % CC;
    int sec = o / CC;
    int ol = o - sec * CC;
    wbf[(size_t)sec * CC * CC + (size_t)(k >> 3) * CC * 8 + ol * 8 + (k & 7)] = bfu(w[idx]);
}

// ---- transpose to MFMA-B layout: src [b][c][p] (fp32 or bf16) -> T [b][c/8][p][8c] bf16
// grid (8, 24, 16), block 256; thread owns 4 consecutive p for one 8-c group.
template<int SRC>
__global__ __launch_bounds__(256) void k_trans(
    const float* __restrict__ xf, const ushort* __restrict__ xh,
    ushort* __restrict__ T)
{
    const int b = blockIdx.x, cg = blockIdx.y;
    const int p = blockIdx.z * 1024 + threadIdx.x * 4;
    float a[8][4];
    #pragma unroll
    for (int c = 0; c < 8; c++) {
        if (SRC == 0) {
            *(float4*)a[c] = *(const float4*)(xf + ((size_t)(b * CC + cg * 8 + c) * HW + p));
        } else {
            ushort4 u = *(const ushort4*)(xh + ((size_t)(b * CC + cg * 8 + c) * HW + p));
            a[c][0] = ubf(u.x); a[c][1] = ubf(u.y); a[c][2] = ubf(u.z); a[c][3] = ubf(u.w);
        }
    }
    #pragma unroll
    for (int j = 0; j < 4; j++) {
        unsigned wp[4];
        #pragma unroll
        for (int i = 0; i < 4; i++)
            wp[i] = (unsigned)bfu(a[2*i][j]) | ((unsigned)bfu(a[2*i+1][j]) << 16);
        *(uint4*)(T + ((size_t)(b * 24 + cg) * HW + p + j) * 8) = *(const uint4*)wp;
    }
}

// ---- LDS-free MFMA GEMM, all loads coalesced.
// A in fragment order [kg16][row][8]; B in [kg16-ish][p][8] (xT/vT).
// MODE0: A=wPack (3 sections) -> q,k,v bf16 planes; MODE1: A=MPack[b] -> fp32 out.
template<int MODE>
__global__ __launch_bounds__(256) void gemm_mfma(
    const ushort* __restrict__ A,
    const ushort* __restrict__ BT,
    ushort* __restrict__ qk, ushort* __restrict__ vpl,
    float* __restrict__ outf)
{
    __shared__ ushort Rep[MODE == 0 ? 192 * 136 : 8];
    int lin = blockIdx.x, sec, pt, b;
    if (MODE == 0) {
        int logical = (lin & 7) * 384 + (lin >> 3);   // XCD-contiguous (3072/8=384)
        sec = logical % 3;
        int pb = logical / 3;
        pt = pb & 127; b = pb >> 7;
    } else {
        int logical = (lin & 7) * 128 + (lin >> 3);   // each XCD owns one batch
        sec = 0; b = logical >> 7; pt = logical & 127;
    }
    const int t = threadIdx.x, lane = t & 63, w = t >> 6;
    const int wr = w >> 1, wc = w & 1;
    const int ll = lane & 31, kg = lane >> 5;
    const int pbase = pt * 128;
    const ushort* Ab = A + (size_t)(MODE == 0 ? sec : b) * CC * CC;
    const ushort* Bb = BT + (size_t)b * 24 * HW * 8;

    f16v acc[3][2];
    #pragma unroll
    for (int mt = 0; mt < 3; mt++)
        #pragma unroll
        for (int nt = 0; nt < 2; nt++)
            #pragma unroll
            for (int i = 0; i < 16; i++) acc[mt][nt][i] = 0.f;

    #pragma unroll 4
    for (int ks = 0; ks < 12; ks++) {
        s8v af[3], bfr[2];
        #pragma unroll
        for (int mt = 0; mt < 3; mt++)
            af[mt] = *(const s8v*)(Ab + ((size_t)(ks * 2 + kg) * CC + wr * 96 + mt * 32 + ll) * 8);
        #pragma unroll
        for (int nt = 0; nt < 2; nt++)
            bfr[nt] = *(const s8v*)(Bb + ((size_t)(ks * 2 + kg) * HW + pbase + wc * 64 + nt * 32 + ll) * 8);
        #pragma unroll
        for (int mt = 0; mt < 3; mt++)
            #pragma unroll
            for (int nt = 0; nt < 2; nt++)
                acc[mt][nt] = __builtin_amdgcn_mfma_f32_32x32x16_bf16(af[mt], bfr[nt], acc[mt][nt], 0, 0, 0);
    }

    if (MODE == 0) {
        // scatter acc -> LDS [o][p] (pad 136), then coalesced 16B stores
        #pragma unroll
        for (int mt = 0; mt < 3; mt++)
            #pragma unroll
            for (int nt = 0; nt < 2; nt++)
                #pragma unroll
                for (int g = 0; g < 4; g++)
                    #pragma unroll
                    for (int j = 0; j < 4; j++)
                        Rep[(wr * 96 + mt * 32 + 8 * g + 4 * kg + j) * 136
                            + wc * 64 + nt * 32 + ll] = bfu(acc[mt][nt][4 * g + j]);
        __syncthreads();
        ushort* ob = (sec == 2) ? vpl + (size_t)b * CC * HW
                                : qk + (size_t)(sec * BB + b) * CC * HW;
        #pragma unroll
        for (int i = 0; i < 12; i++) {
            int idx = i * 256 + t;           // 3072 chunks of 8 ushorts
            int row = idx >> 4, c8 = idx & 15;
            int4 vv = *(const int4*)&Rep[row * 136 + c8 * 8];
            *(int4*)(ob + (size_t)row * HW + pbase + c8 * 8) = vv;
        }
    } else {
        #pragma unroll
        for (int mt = 0; mt < 3; mt++)
            #pragma unroll
            for (int nt = 0; nt < 2; nt++)
                #pragma unroll
                for (int r = 0; r < 16; r++) {
                    int o = wr * 96 + mt * 32 + (r & 3) + 8 * (r >> 2) + 4 * kg;
                    int p = pbase + wc * 64 + nt * 32 + ll;
                    outf[((size_t)b * CC + o) * HW + p] = acc[mt][nt][r];
                }
    }
}

// ---- in-place depthwise 3x3 on bf16 planes + exact fp32 sum-of-squares for q/k
__global__ __launch_bounds__(256) void k_dw_bf(
    ushort* __restrict__ qk, ushort* __restrict__ vb,
    const float* __restrict__ wdw, float* __restrict__ sq, float* __restrict__ sk)
{
    __shared__ ushort rows[10][128];
    __shared__ float red[4];
    int pid = blockIdx.x;
    int sec = pid / NPLANE, rem = pid % NPLANE;
    int b = rem / CC, c = rem % CC;
    ushort* p = sec < 2 ? qk + ((size_t)(sec * BB + b) * CC + c) * HW
                        : vb + ((size_t)b * CC + c) * HW;
    const float* wc9 = wdw + (size_t)(sec * CC + c) * 9;
    float w0=wc9[0],w1=wc9[1],w2=wc9[2],w3=wc9[3],w4=wc9[4],w5=wc9[5],w6=wc9[6],w7=wc9[7],w8=wc9[8];
    const int t = threadIdx.x, lr = t >> 5, lx = (t & 31) * 4;
    float ss = 0.f;
    if (t < 32) ((ushort4*)rows[0])[t] = ((const ushort4*)p)[t];
    __syncthreads();
    for (int y0 = 0; y0 < 128; y0 += 8) {
        int ry = y0 + 1 + lr;
        if (ry < 128) *(ushort4*)&rows[ry % 10][lx] = *(const ushort4*)(p + (size_t)ry * 128 + lx);
        __syncthreads();
        const int oy = y0 + lr;
        float a0=0,a1=0,a2=0,a3=0;
        if (oy >= 1) {
            const ushort* rw = rows[(oy - 1) % 10];
            float m0=ubf(rw[lx]),m1=ubf(rw[lx+1]),m2=ubf(rw[lx+2]),m3=ubf(rw[lx+3]);
            float lf = lx ? ubf(rw[lx-1]) : 0.f, rt = (lx < 124) ? ubf(rw[lx+4]) : 0.f;
            a0 += w0*lf + w1*m0 + w2*m1;  a1 += w0*m0 + w1*m1 + w2*m2;
            a2 += w0*m1 + w1*m2 + w2*m3;  a3 += w0*m2 + w1*m3 + w2*rt;
        }
        {
            const ushort* rw = rows[oy % 10];
            float m0=ubf(rw[lx]),m1=ubf(rw[lx+1]),m2=ubf(rw[lx+2]),m3=ubf(rw[lx+3]);
            float lf = lx ? ubf(rw[lx-1]) : 0.f, rt = (lx < 124) ? ubf(rw[lx+4]) : 0.f;
            a0 += w3*lf + w4*m0 + w5*m1;  a1 += w3*m0 + w4*m1 + w5*m2;
            a2 += w3*m1 + w4*m2 + w5*m3;  a3 += w3*m2 + w4*m3 + w5*rt;
        }
        if (oy + 1 < 128) {
            const ushort* rw = rows[(oy + 1) % 10];
            float m0=ubf(rw[lx]),m1=ubf(rw[lx+1]),m2=ubf(rw[lx+2]),m3=ubf(rw[lx+3]);
            float lf = lx ? ubf(rw[lx-1]) : 0.f, rt = (lx < 124) ? ubf(rw[lx+4]) : 0.f;
            a0 += w6*lf + w7*m0 + w8*m1;  a1 += w6*m0 + w7*m1 + w8*m2;
            a2 += w6*m1 + w7*m2 + w8*m3;  a3 += w6*m2 + w7*m3 + w8*rt;
        }
        ss += a0*a0 + a1*a1 + a2*a2 + a3*a3;
        __syncthreads();
        ushort4 o4; o4.x = bfu(a0); o4.y = bfu(a1); o4.z = bfu(a2); o4.w = bfu(a3);
        *(ushort4*)(p + (size_t)oy * 128 + lx) = o4;
    }
    if (sec < 2) {
        for (int off = 32; off; off >>= 1) ss += __shfl_down(ss, off);
        if ((t & 63) == 0) red[t >> 6] = ss;
        __syncthreads();
        if (t == 0) (sec == 0 ? sq : sk)[b * CC + c] = red[0] + red[1] + red[2] + red[3];
    }
}

// ---- Gram via MFMA 16x16x32, operands direct from global (n-contiguous per lane)
__global__ __launch_bounds__(256) void k_gram(
    const ushort* __restrict__ qk, float* __restrict__ G)
{
    int slab = blockIdx.x, h = blockIdx.y, b = blockIdx.z;
    const int t = threadIdx.x, lane = t & 63, w = t >> 6;
    const ushort* qb = qk + ((size_t)b * CC + h * CHD) * HW;
    const ushort* kb = qk + ((size_t)(BB + b) * CC + h * CHD) * HW;
    const int ll = lane & 15, lh = lane >> 4;
    f4v acc[3][3];
    #pragma unroll
    for (int i = 0; i < 3; i++)
        #pragma unroll
        for (int j = 0; j < 3; j++)
            #pragma unroll
            for (int r = 0; r < 4; r++) acc[i][j][r] = 0.f;
    const int nbase = slab * 1024 + w * 256 + lh * 8;
    for (int s = 0; s < 8; s++) {
        const int n = nbase + s * 32;
        s8v aq[3], bk[3];
        #pragma unroll
        for (int mt = 0; mt < 3; mt++)
            aq[mt] = *(const s8v*)(qb + (size_t)(mt * 16 + ll) * HW + n);
        #pragma unroll
        for (int mt = 0; mt < 3; mt++)
            bk[mt] = *(const s8v*)(kb + (size_t)(mt * 16 + ll) * HW + n);
        #pragma unroll
        for (int i = 0; i < 3; i++)
            #pragma unroll
            for (int j = 0; j < 3; j++)
                acc[i][j] = __builtin_amdgcn_mfma_f32_16x16x32_bf16(aq[i], bk[j], acc[i][j], 0, 0, 0);
    }
    float* Gb = G + (size_t)(b * HEADS + h) * CHD * CHD;
    #pragma unroll
    for (int i = 0; i < 3; i++)
        #pragma unroll
        for (int j = 0; j < 3; j++)
            #pragma unroll
            for (int r = 0; r < 4; r++) {
                int c = i * 16 + lh * 4 + r, d = j * 16 + ll;
                atomicAdd(&Gb[c * CHD + d], acc[i][j][r]);
            }
}

// ---- attn = relu(G*temp/(|q||k|)); MPack[b][c/8][o][c&7] = sum over attn (bf16, A-frag order)
__global__ __launch_bounds__(256) void k_compose(
    const float* __restrict__ G, const float* __restrict__ sq, const float* __restrict__ sk,
    const float* __restrict__ temp, const float* __restrict__ wproj,
    ushort* __restrict__ Mbf)
{
    __shared__ float attnS[CHD * CHD];
    __shared__ float wS[CC * CHD];
    int h = blockIdx.x, b = blockIdx.y, t = threadIdx.x;
    float tv = temp[h];
    const float* Gb = G + (size_t)(b * HEADS + h) * CHD * CHD;
    const float* sqb = sq + b * CC + h * CHD;
    const float* skb = sk + b * CC + h * CHD;
    #pragma unroll
    for (int i = 0; i < 9; i++) {
        int idx = i * 256 + t;
        int c = idx / CHD, d = idx % CHD;
        float nq = fmaxf(sqrtf(sqb[c]), 1e-12f);
        float nk = fmaxf(sqrtf(skb[d]), 1e-12f);
        float v = Gb[idx] * tv / (nq * nk);
        attnS[idx] = fmaxf(v, 0.f);
    }
    #pragma unroll
    for (int i = 0; i < 36; i++) {
        int idx = i * 256 + t;
        wS[idx] = wproj[(idx / CHD) * CC + h * CHD + idx % CHD];
    }
    __syncthreads();
    ushort* Mb = Mbf + (size_t)b * CC * CC;
    #pragma unroll
    for (int i = 0; i < 36; i++) {
        int idx = i * 256 + t;
        int o = idx / CHD, d = idx % CHD;
        float s = 0.f;
        #pragma unroll 8
        for (int c2 = 0; c2 < CHD; c2++)
            s += wS[o * CHD + c2] * attnS[c2 * CHD + d];
        int cglob = h * CHD + d;          // contraction index
        Mb[(size_t)(cglob >> 3) * CC * 8 + o * 8 + (cglob & 7)] = bfu(s);
    }
}

extern "C" void kernel_launch(void* const* d_in, const int* in_sizes, int n_in,
                              void* d_out, int out_size, void* d_ws, size_t ws_size,
                              hipStream_t stream)
{
    const float* x      = (const float*)d_in[0];
    const float* w_qkv  = (const float*)d_in[1];
    const float* w_dw   = (const float*)d_in[2];
    const float* w_proj = (const float*)d_in[3];
    const float* temp   = (const float*)d_in[4];
    float* out = (float*)d_out;

    // d_out doubles as q_bf/k_bf planes (exactly out_size*4 bytes)
    ushort* qk = (ushort*)d_out;

    // ws layout (~97.1 MB): [xT/vT][v planes][G][sq][sk][wbf][Mbf]
    ushort* xT = (ushort*)d_ws;                        // 25,165,824 u16 (reused as vT)
    ushort* vb = xT + (size_t)BB * CC * HW;            // 25,165,824 u16
    float*  G  = (float*)(vb + (size_t)BB * CC * HW);  // 73,728 f
    float*  sq = G + (size_t)BB * HEADS * CHD * CHD;   // 1,536 f
    float*  sk = sq + (size_t)BB * CC;                 // 1,536 f
    ushort* wbf = (ushort*)(sk + (size_t)BB * CC);     // 110,592 u16
    ushort* Mbf = wbf + (size_t)C3 * CC;               // 294,912 u16

    kw_cvt<<<dim3((C3 * CC + 255) / 256), 256, 0, stream>>>(w_qkv, wbf);
    hipMemsetAsync(G, 0, (size_t)BB * HEADS * CHD * CHD * sizeof(float), stream);

    // x -> xT (bf16, MFMA-B layout)
    k_trans<0><<<dim3(BB, 24, 16), 256, 0, stream>>>(x, nullptr, xT);

    // fused qkv GEMM: q,k -> d_out planes, v -> vb planes
    gemm_mfma<0><<<dim3(3072), 256, 0, stream>>>(wbf, xT, qk, vb, nullptr);

    // depthwise 3x3 in place on all planes + exact sum-of-squares for q/k
    k_dw_bf<<<dim3(3 * NPLANE), 256, 0, stream>>>(qk, vb, w_dw, sq, sk);

    // v planes -> vT (reuses xT slot; xT dead after gemm0)
    k_trans<1><<<dim3(BB, 24, 16), 256, 0, stream>>>(nullptr, vb, xT);

    // channel Gram per (b,head)
    k_gram<<<dim3(16, HEADS, BB), 256, 0, stream>>>(qk, G);

    // attn + fold output projection into per-batch M (bf16, fragment order)
    k_compose<<<dim3(HEADS, BB), 256, 0, stream>>>(G, sq, sk, temp, w_proj, Mbf);

    // out = M_b @ v_dw (fp32, overwrites q/k region of d_out)
    gemm_mfma<1><<<dim3(1024), 256, 0, stream>>>(Mbf, xT, nullptr, nullptr, out);
}

// Round 9
// 398.378 us; speedup vs baseline: 2.0251x; 1.0072x over previous
//
#include <hip/hip_runtime.h>

#define BB 8
#define CC 192
#define C3 576
#define HW 16384
#define HEADS 4
#define CHD 48
#define NPLANE (BB*CC)

typedef short s8v __attribute__((ext_vector_type(8)));
typedef float f16v __attribute__((ext_vector_type(16)));
typedef float f4v __attribute__((ext_vector_type(4)));

__device__ __forceinline__ ushort bfu(float f) {
    union { float f; unsigned u; } c; c.f = f;
    unsigned u = c.u + 0x7FFFu + ((c.u >> 16) & 1u);
    return (ushort)(u >> 16);
}
__device__ __forceinline__ float ubf(ushort u) {
    union { unsigned u; float f; } c; c.u = ((unsigned)u) << 16;
    return c.f;
}

// ---- convert w_qkv fp32 [576][192] -> bf16 in MFMA A-fragment order:
// wPack[sec][kg16 = k/8][row = o%192][k&7]
__global__ void kw_cvt(const float* __restrict__ w, ushort* __restrict__ wbf) {
    int idx = blockIdx.x * 256 + threadIdx.x;
    if (idx >= C3 * CC) return;
    int o = idx / CC, k = idx % CC;
    int sec = o / CC;
    int ol = o - sec * CC;
    wbf[(size_t)sec * CC * CC + (size_t)(k >> 3) * CC * 8 + ol * 8 + (k & 7)] = bfu(w[idx]);
}

// ---- transpose to MFMA-B layout: x [b][c][p] fp32 -> T [b][c/8][p][8c] bf16
__global__ __launch_bounds__(256) void k_trans(
    const float* __restrict__ xf, ushort* __restrict__ T)
{
    const int b = blockIdx.x, cg = blockIdx.y;
    const int p = blockIdx.z * 1024 + threadIdx.x * 4;
    float a[8][4];
    #pragma unroll
    for (int c = 0; c < 8; c++)
        *(float4*)a[c] = *(const float4*)(xf + ((size_t)(b * CC + cg * 8 + c) * HW + p));
    #pragma unroll
    for (int j = 0; j < 4; j++) {
        unsigned wp[4];
        #pragma unroll
        for (int i = 0; i < 4; i++)
            wp[i] = (unsigned)bfu(a[2*i][j]) | ((unsigned)bfu(a[2*i+1][j]) << 16);
        *(uint4*)(T + ((size_t)(b * 24 + cg) * HW + p + j) * 8) = *(const uint4*)wp;
    }
}

__device__ __forceinline__ void loadk(int ks, const ushort* Ab, const ushort* Bb,
    int kg, int wr, int wc, int ll, int pbase, s8v a[3], s8v b[2])
{
    #pragma unroll
    for (int mt = 0; mt < 3; mt++)
        a[mt] = *(const s8v*)(Ab + ((size_t)(ks * 2 + kg) * CC + wr * 96 + mt * 32 + ll) * 8);
    #pragma unroll
    for (int nt = 0; nt < 2; nt++)
        b[nt] = *(const s8v*)(Bb + ((size_t)(ks * 2 + kg) * HW + pbase + wc * 64 + nt * 32 + ll) * 8);
}

// ---- LDS-free MFMA GEMM, reg ping-pong prefetch, direct stores.
// MODE0: A=wPack (3 sections) -> q,k planes (d_out) + v planes; MODE1: A=MPack[b] -> fp32 out.
template<int MODE>
__global__ __launch_bounds__(256) void gemm_mfma(
    const ushort* __restrict__ A,
    const ushort* __restrict__ BT,
    ushort* __restrict__ qk, ushort* __restrict__ vpl,
    float* __restrict__ outf)
{
    int lin = blockIdx.x, sec, pt, b;
    if (MODE == 0) {
        int logical = (lin & 7) * 384 + (lin >> 3);   // XCD-contiguous (3072/8=384)
        sec = logical % 3;
        int pb = logical / 3;
        pt = pb & 127; b = pb >> 7;
    } else {
        int logical = (lin & 7) * 128 + (lin >> 3);   // each XCD owns one batch
        sec = 0; b = logical >> 7; pt = logical & 127;
    }
    const int t = threadIdx.x, lane = t & 63, w = t >> 6;
    const int wr = w >> 1, wc = w & 1;
    const int ll = lane & 31, kg = lane >> 5;
    const int pbase = pt * 128;
    const ushort* Ab = A + (size_t)(MODE == 0 ? sec : b) * CC * CC;
    const ushort* Bb = BT + (size_t)b * 24 * HW * 8;

    f16v acc[3][2];
    #pragma unroll
    for (int mt = 0; mt < 3; mt++)
        #pragma unroll
        for (int nt = 0; nt < 2; nt++)
            #pragma unroll
            for (int i = 0; i < 16; i++) acc[mt][nt][i] = 0.f;

    s8v a0[3], b0[2], a1[3], b1[2];
    loadk(0, Ab, Bb, kg, wr, wc, ll, pbase, a0, b0);
    #pragma unroll
    for (int kk = 0; kk < 6; kk++) {
        loadk(2 * kk + 1, Ab, Bb, kg, wr, wc, ll, pbase, a1, b1);
        #pragma unroll
        for (int mt = 0; mt < 3; mt++)
            #pragma unroll
            for (int nt = 0; nt < 2; nt++)
                acc[mt][nt] = __builtin_amdgcn_mfma_f32_32x32x16_bf16(a0[mt], b0[nt], acc[mt][nt], 0, 0, 0);
        if (kk < 5) loadk(2 * kk + 2, Ab, Bb, kg, wr, wc, ll, pbase, a0, b0);
        #pragma unroll
        for (int mt = 0; mt < 3; mt++)
            #pragma unroll
            for (int nt = 0; nt < 2; nt++)
                acc[mt][nt] = __builtin_amdgcn_mfma_f32_32x32x16_bf16(a1[mt], b1[nt], acc[mt][nt], 0, 0, 0);
    }

    if (MODE == 0) {
        ushort* ob = (sec == 2) ? vpl + (size_t)b * CC * HW
                                : qk + (size_t)(sec * BB + b) * CC * HW;
        #pragma unroll
        for (int mt = 0; mt < 3; mt++)
            #pragma unroll
            for (int nt = 0; nt < 2; nt++)
                #pragma unroll
                for (int r = 0; r < 16; r++) {
                    int o = wr * 96 + mt * 32 + (r & 3) + 8 * (r >> 2) + 4 * kg;
                    int p = pbase + wc * 64 + nt * 32 + ll;
                    ob[(size_t)o * HW + p] = bfu(acc[mt][nt][r]);
                }
    } else {
        #pragma unroll
        for (int mt = 0; mt < 3; mt++)
            #pragma unroll
            for (int nt = 0; nt < 2; nt++)
                #pragma unroll
                for (int r = 0; r < 16; r++) {
                    int o = wr * 96 + mt * 32 + (r & 3) + 8 * (r >> 2) + 4 * kg;
                    int p = pbase + wc * 64 + nt * 32 + ll;
                    outf[((size_t)b * CC + o) * HW + p] = acc[mt][nt][r];
                }
    }
}

// ---- in-place depthwise 3x3 on q/k bf16 planes + exact fp32 sum-of-squares
__global__ __launch_bounds__(256) void k_dw_bf(
    ushort* __restrict__ qk,
    const float* __restrict__ wdw, float* __restrict__ sq, float* __restrict__ sk)
{
    __shared__ ushort rows[10][128];
    __shared__ float red[4];
    int pid = blockIdx.x;
    int sec = pid / NPLANE, rem = pid % NPLANE;
    int b = rem / CC, c = rem % CC;
    ushort* p = qk + ((size_t)(sec * BB + b) * CC + c) * HW;
    const float* wc9 = wdw + (size_t)(sec * CC + c) * 9;
    float w0=wc9[0],w1=wc9[1],w2=wc9[2],w3=wc9[3],w4=wc9[4],w5=wc9[5],w6=wc9[6],w7=wc9[7],w8=wc9[8];
    const int t = threadIdx.x, lr = t >> 5, lx = (t & 31) * 4;
    float ss = 0.f;
    if (t < 32) ((ushort4*)rows[0])[t] = ((const ushort4*)p)[t];
    __syncthreads();
    for (int y0 = 0; y0 < 128; y0 += 8) {
        int ry = y0 + 1 + lr;
        if (ry < 128) *(ushort4*)&rows[ry % 10][lx] = *(const ushort4*)(p + (size_t)ry * 128 + lx);
        __syncthreads();
        const int oy = y0 + lr;
        float a0=0,a1=0,a2=0,a3=0;
        if (oy >= 1) {
            const ushort* rw = rows[(oy - 1) % 10];
            float m0=ubf(rw[lx]),m1=ubf(rw[lx+1]),m2=ubf(rw[lx+2]),m3=ubf(rw[lx+3]);
            float lf = lx ? ubf(rw[lx-1]) : 0.f, rt = (lx < 124) ? ubf(rw[lx+4]) : 0.f;
            a0 += w0*lf + w1*m0 + w2*m1;  a1 += w0*m0 + w1*m1 + w2*m2;
            a2 += w0*m1 + w1*m2 + w2*m3;  a3 += w0*m2 + w1*m3 + w2*rt;
        }
        {
            const ushort* rw = rows[oy % 10];
            float m0=ubf(rw[lx]),m1=ubf(rw[lx+1]),m2=ubf(rw[lx+2]),m3=ubf(rw[lx+3]);
            float lf = lx ? ubf(rw[lx-1]) : 0.f, rt = (lx < 124) ? ubf(rw[lx+4]) : 0.f;
            a0 += w3*lf + w4*m0 + w5*m1;  a1 += w3*m0 + w4*m1 + w5*m2;
            a2 += w3*m1 + w4*m2 + w5*m3;  a3 += w3*m2 + w4*m3 + w5*rt;
        }
        if (oy + 1 < 128) {
            const ushort* rw = rows[(oy + 1) % 10];
            float m0=ubf(rw[lx]),m1=ubf(rw[lx+1]),m2=ubf(rw[lx+2]),m3=ubf(rw[lx+3]);
            float lf = lx ? ubf(rw[lx-1]) : 0.f, rt = (lx < 124) ? ubf(rw[lx+4]) : 0.f;
            a0 += w6*lf + w7*m0 + w8*m1;  a1 += w6*m0 + w7*m1 + w8*m2;
            a2 += w6*m1 + w7*m2 + w8*m3;  a3 += w6*m2 + w7*m3 + w8*rt;
        }
        ss += a0*a0 + a1*a1 + a2*a2 + a3*a3;
        __syncthreads();
        ushort4 o4; o4.x = bfu(a0); o4.y = bfu(a1); o4.z = bfu(a2); o4.w = bfu(a3);
        *(ushort4*)(p + (size_t)oy * 128 + lx) = o4;
    }
    for (int off = 32; off; off >>= 1) ss += __shfl_down(ss, off);
    if ((t & 63) == 0) red[t >> 6] = ss;
    __syncthreads();
    if (t == 0) (sec == 0 ? sq : sk)[b * CC + c] = red[0] + red[1] + red[2] + red[3];
}

// ---- depthwise 3x3 on v planes, output directly in vT (MFMA-B) layout.
// Not in place: reads vb, writes vT. grid (24, BB, 4), block 256.
__global__ __launch_bounds__(256) void k_dw_v(
    const ushort* __restrict__ vb, const float* __restrict__ wdw,
    ushort* __restrict__ vT)
{
    __shared__ ushort obuf[4][8][128];
    const int cg = blockIdx.x, b = blockIdx.y, yq = blockIdx.z;
    const int t = threadIdx.x;
    const int c = t >> 5, lr = (t >> 3) & 3, xo = t & 7;
    const int ch = cg * 8 + c;
    const ushort* p = vb + ((size_t)b * CC + ch) * HW;
    const float* wc9 = wdw + (size_t)(2 * CC + ch) * 9;
    float wt[9];
    #pragma unroll
    for (int i = 0; i < 9; i++) wt[i] = wc9[i];
    ushort* tb = vT + (size_t)(b * 24 + cg) * HW * 8;
    const int x0 = xo * 16;

    for (int ic = 0; ic < 8; ic++) {
        const int y = yq * 32 + ic * 4 + lr;
        float a[16];
        #pragma unroll
        for (int j = 0; j < 16; j++) a[j] = 0.f;
        #pragma unroll
        for (int dy = 0; dy < 3; dy++) {
            int ry = y - 1 + dy;
            if (ry >= 0 && ry < 128) {
                const ushort* r = p + (size_t)ry * 128 + x0;
                float wv[18];
                uint4 v0 = *(const uint4*)r;
                uint4 v1 = *(const uint4*)(r + 8);
                unsigned uu[8] = {v0.x, v0.y, v0.z, v0.w, v1.x, v1.y, v1.z, v1.w};
                #pragma unroll
                for (int q = 0; q < 8; q++) {
                    union { unsigned u; float f; } lo, hi;
                    lo.u = uu[q] << 16;  hi.u = uu[q] & 0xFFFF0000u;
                    wv[1 + 2*q] = lo.f;  wv[2 + 2*q] = hi.f;
                }
                wv[0]  = x0 ? ubf(r[-1]) : 0.f;
                wv[17] = (x0 < 112) ? ubf(r[16]) : 0.f;
                float t0 = wt[dy*3], t1 = wt[dy*3+1], t2 = wt[dy*3+2];
                #pragma unroll
                for (int j = 0; j < 16; j++)
                    a[j] += t0 * wv[j] + t1 * wv[j+1] + t2 * wv[j+2];
            }
        }
        __syncthreads();   // prev gather done before overwrite
        ushort tmp[16];
        #pragma unroll
        for (int j = 0; j < 16; j++) tmp[j] = bfu(a[j]);
        *(int4*)&obuf[lr][c][x0]     = *(int4*)&tmp[0];
        *(int4*)&obuf[lr][c][x0 + 8] = *(int4*)&tmp[8];
        __syncthreads();
        #pragma unroll
        for (int rep = 0; rep < 2; rep++) {
            int u = t + rep * 256;
            int row = u >> 7, x = u & 127;
            int4 gi;
            ushort* g = (ushort*)&gi;
            #pragma unroll
            for (int cc = 0; cc < 8; cc++) g[cc] = obuf[row][cc][x];
            int yg = yq * 32 + ic * 4 + row;
            *(int4*)(tb + ((size_t)yg * 128 + x) * 8) = gi;
        }
    }
}

// ---- Gram via MFMA 16x16x32, strided global operands; 32 slabs for occupancy
__global__ __launch_bounds__(256) void k_gram(
    const ushort* __restrict__ qk, float* __restrict__ G)
{
    int slab = blockIdx.x, h = blockIdx.y, b = blockIdx.z;
    const int t = threadIdx.x, lane = t & 63, w = t >> 6;
    const ushort* qb = qk + ((size_t)b * CC + h * CHD) * HW;
    const ushort* kb = qk + ((size_t)(BB + b) * CC + h * CHD) * HW;
    const int ll = lane & 15, lh = lane >> 4;
    f4v acc[3][3];
    #pragma unroll
    for (int i = 0; i < 3; i++)
        #pragma unroll
        for (int j = 0; j < 3; j++)
            #pragma unroll
            for (int r = 0; r < 4; r++) acc[i][j][r] = 0.f;
    const int nbase = slab * 512 + w * 128 + lh * 8;
    #pragma unroll
    for (int s = 0; s < 4; s++) {
        const int n = nbase + s * 32;
        s8v aq[3], bk[3];
        #pragma unroll
        for (int mt = 0; mt < 3; mt++)
            aq[mt] = *(const s8v*)(qb + (size_t)(mt * 16 + ll) * HW + n);
        #pragma unroll
        for (int mt = 0; mt < 3; mt++)
            bk[mt] = *(const s8v*)(kb + (size_t)(mt * 16 + ll) * HW + n);
        #pragma unroll
        for (int i = 0; i < 3; i++)
            #pragma unroll
            for (int j = 0; j < 3; j++)
                acc[i][j] = __builtin_amdgcn_mfma_f32_16x16x32_bf16(aq[i], bk[j], acc[i][j], 0, 0, 0);
    }
    float* Gb = G + (size_t)(b * HEADS + h) * CHD * CHD;
    #pragma unroll
    for (int i = 0; i < 3; i++)
        #pragma unroll
        for (int j = 0; j < 3; j++)
            #pragma unroll
            for (int r = 0; r < 4; r++) {
                int cc = i * 16 + lh * 4 + r, d = j * 16 + ll;
                atomicAdd(&Gb[cc * CHD + d], acc[i][j][r]);
            }
}

// ---- attn = relu(G*temp/(|q||k|)); MPack[b][c/8][o][c&7] (bf16, A-frag order)
__global__ __launch_bounds__(256) void k_compose(
    const float* __restrict__ G, const float* __restrict__ sq, const float* __restrict__ sk,
    const float* __restrict__ temp, const float* __restrict__ wproj,
    ushort* __restrict__ Mbf)
{
    __shared__ float attnS[CHD * CHD];
    __shared__ float wS[CC * CHD];
    int h = blockIdx.x, b = blockIdx.y, t = threadIdx.x;
    float tv = temp[h];
    const float* Gb = G + (size_t)(b * HEADS + h) * CHD * CHD;
    const float* sqb = sq + b * CC + h * CHD;
    const float* skb = sk + b * CC + h * CHD;
    #pragma unroll
    for (int i = 0; i < 9; i++) {
        int idx = i * 256 + t;
        int c = idx / CHD, d = idx % CHD;
        float nq = fmaxf(sqrtf(sqb[c]), 1e-12f);
        float nk = fmaxf(sqrtf(skb[d]), 1e-12f);
        float v = Gb[idx] * tv / (nq * nk);
        attnS[idx] = fmaxf(v, 0.f);
    }
    #pragma unroll
    for (int i = 0; i < 36; i++) {
        int idx = i * 256 + t;
        wS[idx] = wproj[(idx / CHD) * CC + h * CHD + idx % CHD];
    }
    __syncthreads();
    ushort* Mb = Mbf + (size_t)b * CC * CC;
    #pragma unroll
    for (int i = 0; i < 36; i++) {
        int idx = i * 256 + t;
        int o = idx / CHD, d = idx % CHD;
        float s = 0.f;
        #pragma unroll 8
        for (int c2 = 0; c2 < CHD; c2++)
            s += wS[o * CHD + c2] * attnS[c2 * CHD + d];
        int cglob = h * CHD + d;          // contraction index
        Mb[(size_t)(cglob >> 3) * CC * 8 + o * 8 + (cglob & 7)] = bfu(s);
    }
}

extern "C" void kernel_launch(void* const* d_in, const int* in_sizes, int n_in,
                              void* d_out, int out_size, void* d_ws, size_t ws_size,
                              hipStream_t stream)
{
    const float* x      = (const float*)d_in[0];
    const float* w_qkv  = (const float*)d_in[1];
    const float* w_dw   = (const float*)d_in[2];
    const float* w_proj = (const float*)d_in[3];
    const float* temp   = (const float*)d_in[4];
    float* out = (float*)d_out;

    // d_out doubles as q_bf/k_bf planes (exactly out_size*4 bytes)
    ushort* qk = (ushort*)d_out;

    // ws layout (~97.1 MB): [xT(->vT)][v planes][G][sq][sk][wbf][Mbf]
    ushort* xT = (ushort*)d_ws;                        // 25,165,824 u16 (reused as vT)
    ushort* vb = xT + (size_t)BB * CC * HW;            // 25,165,824 u16
    float*  G  = (float*)(vb + (size_t)BB * CC * HW);  // 73,728 f
    float*  sq = G + (size_t)BB * HEADS * CHD * CHD;   // 1,536 f
    float*  sk = sq + (size_t)BB * CC;                 // 1,536 f
    ushort* wbf = (ushort*)(sk + (size_t)BB * CC);     // 110,592 u16
    ushort* Mbf = wbf + (size_t)C3 * CC;               // 294,912 u16

    kw_cvt<<<dim3((C3 * CC + 255) / 256), 256, 0, stream>>>(w_qkv, wbf);
    hipMemsetAsync(G, 0, (size_t)BB * HEADS * CHD * CHD * sizeof(float), stream);

    // x -> xT (bf16, MFMA-B layout)
    k_trans<<<dim3(BB, 24, 16), 256, 0, stream>>>(x, xT);

    // fused qkv GEMM: q,k -> d_out planes, v -> vb planes
    gemm_mfma<0><<<dim3(3072), 256, 0, stream>>>(wbf, xT, qk, vb, nullptr);

    // depthwise 3x3 in place on q/k planes + exact sum-of-squares
    k_dw_bf<<<dim3(2 * NPLANE), 256, 0, stream>>>(qk, w_dw, sq, sk);

    // depthwise 3x3 on v, fused transpose -> vT (xT slot; xT dead after gemm0)
    k_dw_v<<<dim3(24, BB, 4), 256, 0, stream>>>(vb, w_dw, xT);

    // channel Gram per (b,head)
    k_gram<<<dim3(32, HEADS, BB), 256, 0, stream>>>(qk, G);

    // attn + fold output projection into per-batch M (bf16, fragment order)
    k_compose<<<dim3(HEADS, BB), 256, 0, stream>>>(G, sq, sk, temp, w_proj, Mbf);

    // out = M_b @ v_dw (fp32, overwrites q/k region of d_out)
    gemm_mfma<1><<<dim3(1024), 256, 0, stream>>>(Mbf, xT, nullptr, nullptr, out);
}